// Round 4
// baseline (150.280 us; speedup 1.0000x reference)
//
#include <hip/hip_runtime.h>

typedef float f4 __attribute__((ext_vector_type(4)));

#define BB 1024
#define SS 192
#define DD 512
#define NUM_LAYERS 3
#define LN_EPS 1e-5f
#define NROWS (BB * SS)
#define FUSED_BLOCKS 2048
#define NWAVES (FUSED_BLOCKS * 4)
#define NITER (NROWS / NWAVES)          // exactly 24

// Merged prep:
//  blocks [0, SS)      : add_tab[pos] = item_pos[pos/3] + layer[pos%3] + decay[pos/3]
//  blocks [SS, SS+256) : start[b] via ballot; start=SS if row has no content
__global__ __launch_bounds__(256) void prep_kernel(
    const int* __restrict__ mask,
    const float* __restrict__ item_pos,
    const float* __restrict__ layer_emb,
    const float* __restrict__ decay,
    float* __restrict__ add_tab,
    int* __restrict__ start)
{
    if (blockIdx.x < SS) {
        const int p = blockIdx.x;
        const int t = threadIdx.x;
        if (t < DD / 4) {
            const int item = p / NUM_LAYERS;
            const int layer = p - item * NUM_LAYERS;
            const f4 iv = reinterpret_cast<const f4*>(item_pos + item * DD)[t];
            const f4 lv = reinterpret_cast<const f4*>(layer_emb + layer * DD)[t];
            const f4 dv = reinterpret_cast<const f4*>(decay + item * DD)[t];
            reinterpret_cast<f4*>(add_tab + p * DD)[t] = iv + lv + dv;
        }
    } else {
        const int b = (blockIdx.x - SS) * 4 + (threadIdx.x >> 6);
        const int lane = threadIdx.x & 63;
        if (b < BB) {
            const int* m = mask + b * SS;
            const unsigned long long b0 = __ballot(m[lane] > 0);
            const unsigned long long b1 = __ballot(m[lane + 64] > 0);
            const unsigned long long b2 = __ballot(m[lane + 128] > 0);
            int idx;
            if (b0)      idx = __ffsll(b0) - 1;
            else if (b1) idx = 64 + __ffsll(b1) - 1;
            else if (b2) idx = 128 + __ffsll(b2) - 1;
            else         idx = SS;
            if (lane == 0) start[b] = idx;
        }
    }
}

// Persistent waves, software-pipelined: row k+1's loads are issued BEFORE the
// reduce/normalize/store of row k, so HBM loads stay outstanding through the
// ~500-cycle shuffle-reduce phase (duty-cycle fix). Streams use nt hints.
__global__ __launch_bounds__(256) void fused_kernel(
    const float* __restrict__ tok,
    const float* __restrict__ add_tab,
    const float* __restrict__ lnw,
    const float* __restrict__ lnb,
    const int* __restrict__ start,
    float* __restrict__ out)
{
    const int wid = threadIdx.x >> 6;
    const int lane = threadIdx.x & 63;
    const int l0 = lane;
    const int l1 = lane + 64;

    const f4 w0 = reinterpret_cast<const f4*>(lnw)[l0];
    const f4 w1 = reinterpret_cast<const f4*>(lnw)[l1];
    const f4 c0 = reinterpret_cast<const f4*>(lnb)[l0];
    const f4 c1 = reinterpret_cast<const f4*>(lnb)[l1];

    const int wave = blockIdx.x * 4 + wid;

    int row = wave;
    bool cont;
    f4 xv0 = {0.f, 0.f, 0.f, 0.f}, xv1 = {0.f, 0.f, 0.f, 0.f};
    f4 a0  = {0.f, 0.f, 0.f, 0.f}, a1  = {0.f, 0.f, 0.f, 0.f};

    // prologue: fetch first row's state
    {
        const int b = row / SS;
        const int s = row - b * SS;
        const int st = start[b];
        cont = (s >= st);
        if (cont) {
            const f4* x4 = reinterpret_cast<const f4*>(tok + (size_t)row * DD);
            xv0 = __builtin_nontemporal_load(x4 + l0);
            xv1 = __builtin_nontemporal_load(x4 + l1);
            const f4* a4 = reinterpret_cast<const f4*>(add_tab + (s - st) * DD);
            a0 = a4[l0];
            a1 = a4[l1];
        }
    }

    #pragma unroll 1
    for (int k = 0; k < NITER; ++k) {
        const int nrow = row + NWAVES;
        bool ncont = false;
        f4 nx0 = {0.f, 0.f, 0.f, 0.f}, nx1 = {0.f, 0.f, 0.f, 0.f};
        f4 na0 = {0.f, 0.f, 0.f, 0.f}, na1 = {0.f, 0.f, 0.f, 0.f};

        // ---- prefetch next row (loads stay in flight through the reduce) ----
        if (k + 1 < NITER) {
            const int nb = nrow / SS;
            const int ns = nrow - nb * SS;
            const int nst = start[nb];
            ncont = (ns >= nst);
            if (ncont) {
                const f4* x4 = reinterpret_cast<const f4*>(tok + (size_t)nrow * DD);
                nx0 = __builtin_nontemporal_load(x4 + l0);
                nx1 = __builtin_nontemporal_load(x4 + l1);
                const f4* a4 = reinterpret_cast<const f4*>(add_tab + (ns - nst) * DD);
                na0 = a4[l0];
                na1 = a4[l1];
            }
        }

        // ---- finish current row ----
        f4* o4 = reinterpret_cast<f4*>(out + (size_t)row * DD);
        if (!cont) {
            const f4 z = {0.f, 0.f, 0.f, 0.f};
            __builtin_nontemporal_store(z, o4 + l0);
            __builtin_nontemporal_store(z, o4 + l1);
        } else {
            const f4 y0 = xv0 + a0;
            const f4 y1 = xv1 + a1;

            float sum = y0.x + y0.y + y0.z + y0.w + y1.x + y1.y + y1.z + y1.w;
            const f4 q0 = y0 * y0;
            const f4 q1 = y1 * y1;
            float sq = q0.x + q0.y + q0.z + q0.w + q1.x + q1.y + q1.z + q1.w;

            #pragma unroll
            for (int m = 32; m > 0; m >>= 1) {
                sum += __shfl_xor(sum, m, 64);
                sq  += __shfl_xor(sq,  m, 64);
            }

            const float mu  = sum * (1.0f / DD);
            const float var = sq * (1.0f / DD) - mu * mu;
            const float inv = rsqrtf(var + LN_EPS);

            const f4 ov0 = (y0 - mu) * inv * w0 + c0;
            const f4 ov1 = (y1 - mu) * inv * w1 + c1;
            __builtin_nontemporal_store(ov0, o4 + l0);
            __builtin_nontemporal_store(ov1, o4 + l1);
        }

        row = nrow;
        cont = ncont;
        xv0 = nx0; xv1 = nx1;
        a0 = na0;  a1 = na1;
    }
}

extern "C" void kernel_launch(void* const* d_in, const int* in_sizes, int n_in,
                              void* d_out, int out_size, void* d_ws, size_t ws_size,
                              hipStream_t stream) {
    const float* tok       = (const float*)d_in[0];   // (B,S,D)
    const int*   mask      = (const int*)d_in[1];     // (B,S)
    const float* item_pos  = (const float*)d_in[2];   // (64,D)
    const float* layer_emb = (const float*)d_in[3];   // (3,D)
    const float* decay     = (const float*)d_in[4];   // (64,D)
    const float* lnw       = (const float*)d_in[5];   // (D,)
    const float* lnb       = (const float*)d_in[6];   // (D,)
    float* out = (float*)d_out;

    // workspace layout: [ add_tab: SS*DD floats ][ start: BB ints ]
    float* add_tab = (float*)d_ws;
    int* start = (int*)((char*)d_ws + (size_t)SS * DD * sizeof(float));

    prep_kernel<<<SS + 256, 256, 0, stream>>>(mask, item_pos, layer_emb, decay,
                                              add_tab, start);
    fused_kernel<<<FUSED_BLOCKS, 256, 0, stream>>>(tok, add_tab, lnw, lnb, start, out);
}

// Round 5
// 146.395 us; speedup vs baseline: 1.0265x; 1.0265x over previous
//
#include <hip/hip_runtime.h>

typedef float f4 __attribute__((ext_vector_type(4)));

#define BB 1024
#define SS 192
#define DD 512
#define NUM_LAYERS 3
#define LN_EPS 1e-5f
#define NROWS (BB * SS)
#define FUSED_BLOCKS 2048
#define NWAVES (FUSED_BLOCKS * 4)
#define NITER (NROWS / NWAVES)          // exactly 24

// Merged prep:
//  blocks [0, SS)      : add_tab[pos] = item_pos[pos/3] + layer[pos%3] + decay[pos/3]
//  blocks [SS, SS+256) : start[b] via ballot; start=SS if row has no content
__global__ __launch_bounds__(256) void prep_kernel(
    const int* __restrict__ mask,
    const float* __restrict__ item_pos,
    const float* __restrict__ layer_emb,
    const float* __restrict__ decay,
    float* __restrict__ add_tab,
    int* __restrict__ start)
{
    if (blockIdx.x < SS) {
        const int p = blockIdx.x;
        const int t = threadIdx.x;
        if (t < DD / 4) {
            const int item = p / NUM_LAYERS;
            const int layer = p - item * NUM_LAYERS;
            const f4 iv = reinterpret_cast<const f4*>(item_pos + item * DD)[t];
            const f4 lv = reinterpret_cast<const f4*>(layer_emb + layer * DD)[t];
            const f4 dv = reinterpret_cast<const f4*>(decay + item * DD)[t];
            reinterpret_cast<f4*>(add_tab + p * DD)[t] = iv + lv + dv;
        }
    } else {
        const int b = (blockIdx.x - SS) * 4 + (threadIdx.x >> 6);
        const int lane = threadIdx.x & 63;
        if (b < BB) {
            const int* m = mask + b * SS;
            const unsigned long long b0 = __ballot(m[lane] > 0);
            const unsigned long long b1 = __ballot(m[lane + 64] > 0);
            const unsigned long long b2 = __ballot(m[lane + 128] > 0);
            int idx;
            if (b0)      idx = __ffsll(b0) - 1;
            else if (b1) idx = 64 + __ffsll(b1) - 1;
            else if (b2) idx = 128 + __ffsll(b2) - 1;
            else         idx = SS;
            if (lane == 0) start[b] = idx;
        }
    }
}

// Cheap wave64 all-reduce: for SUMS any cross-group pairing tree works, so use
// DPP permutes (VALU latency, no lgkmcnt) for the 4 in-row-16 levels, then one
// ds_swizzle (xor16) and one ds_bpermute (xor32).
//   quad_perm [1,0,3,2] = 0xB1 (xor1), quad_perm [2,3,0,1] = 0x4E (xor2),
//   row_half_mirror = 0x141 (pairs across quads), row_mirror = 0x140 (across 8s)
__device__ __forceinline__ float wave_allreduce(float v, int xaddr32) {
    v += __uint_as_float((unsigned)__builtin_amdgcn_update_dpp(
            0, (int)__float_as_uint(v), 0xB1, 0xF, 0xF, true));
    v += __uint_as_float((unsigned)__builtin_amdgcn_update_dpp(
            0, (int)__float_as_uint(v), 0x4E, 0xF, 0xF, true));
    v += __uint_as_float((unsigned)__builtin_amdgcn_update_dpp(
            0, (int)__float_as_uint(v), 0x141, 0xF, 0xF, true));
    v += __uint_as_float((unsigned)__builtin_amdgcn_update_dpp(
            0, (int)__float_as_uint(v), 0x140, 0xF, 0xF, true));
    // xor16 within 32 lanes: bit-mode offset = (16<<10) | 0x1F
    v += __uint_as_float((unsigned)__builtin_amdgcn_ds_swizzle(
            (int)__float_as_uint(v), 0x401f));
    // cross-32: bpermute with addr = (lane^32)*4 (precomputed)
    v += __uint_as_float((unsigned)__builtin_amdgcn_ds_bpermute(
            xaddr32, (int)__float_as_uint(v)));
    return v;
}

// Persistent waves: one wave per row per iteration; lnw/lnb live in registers.
__global__ __launch_bounds__(256) void fused_kernel(
    const float* __restrict__ tok,
    const float* __restrict__ add_tab,
    const float* __restrict__ lnw,
    const float* __restrict__ lnb,
    const int* __restrict__ start,
    float* __restrict__ out)
{
    const int wid = threadIdx.x >> 6;
    const int lane = threadIdx.x & 63;
    const int l0 = lane;
    const int l1 = lane + 64;
    const int xaddr32 = (lane ^ 32) << 2;   // for cross-32 bpermute

    const f4 w0 = reinterpret_cast<const f4*>(lnw)[l0];
    const f4 w1 = reinterpret_cast<const f4*>(lnw)[l1];
    const f4 c0 = reinterpret_cast<const f4*>(lnb)[l0];
    const f4 c1 = reinterpret_cast<const f4*>(lnb)[l1];

    const int wave = blockIdx.x * 4 + wid;

    #pragma unroll 1
    for (int row = wave; row < NROWS; row += NWAVES) {
        const int b = row / SS;
        const int s = row - b * SS;
        const int st = start[b];

        f4* o4 = reinterpret_cast<f4*>(out + (size_t)row * DD);

        if (s < st) {                        // wave-uniform branch
            const f4 z = {0.f, 0.f, 0.f, 0.f};
            o4[l0] = z;
            o4[l1] = z;
            continue;
        }

        const int pos = s - st;              // 0..191

        const f4* x4 = reinterpret_cast<const f4*>(tok + (size_t)row * DD);
        const f4 xv0 = x4[l0];
        const f4 xv1 = x4[l1];

        const f4* a4 = reinterpret_cast<const f4*>(add_tab + pos * DD);
        const f4 y0 = xv0 + a4[l0];
        const f4 y1 = xv1 + a4[l1];

        float sum = (y0.x + y0.y) + (y0.z + y0.w)
                  + (y1.x + y1.y) + (y1.z + y1.w);
        const f4 q0 = y0 * y0;
        const f4 q1 = y1 * y1;
        float sq = (q0.x + q0.y) + (q0.z + q0.w)
                 + (q1.x + q1.y) + (q1.z + q1.w);

        sum = wave_allreduce(sum, xaddr32);
        sq  = wave_allreduce(sq, xaddr32);

        const float mu  = sum * (1.0f / DD);
        const float var = sq * (1.0f / DD) - mu * mu;
        const float inv = rsqrtf(var + LN_EPS);

        const f4 ov0 = (y0 - mu) * inv * w0 + c0;
        const f4 ov1 = (y1 - mu) * inv * w1 + c1;
        o4[l0] = ov0;
        o4[l1] = ov1;
    }
}

extern "C" void kernel_launch(void* const* d_in, const int* in_sizes, int n_in,
                              void* d_out, int out_size, void* d_ws, size_t ws_size,
                              hipStream_t stream) {
    const float* tok       = (const float*)d_in[0];   // (B,S,D)
    const int*   mask      = (const int*)d_in[1];     // (B,S)
    const float* item_pos  = (const float*)d_in[2];   // (64,D)
    const float* layer_emb = (const float*)d_in[3];   // (3,D)
    const float* decay     = (const float*)d_in[4];   // (64,D)
    const float* lnw       = (const float*)d_in[5];   // (D,)
    const float* lnb       = (const float*)d_in[6];   // (D,)
    float* out = (float*)d_out;

    // workspace layout: [ add_tab: SS*DD floats ][ start: BB ints ]
    float* add_tab = (float*)d_ws;
    int* start = (int*)((char*)d_ws + (size_t)SS * DD * sizeof(float));

    prep_kernel<<<SS + 256, 256, 0, stream>>>(mask, item_pos, layer_emb, decay,
                                              add_tab, start);
    fused_kernel<<<FUSED_BLOCKS, 256, 0, stream>>>(tok, add_tab, lnw, lnb, start, out);
}